// Round 1
// baseline (28264.047 us; speedup 1.0000x reference)
//
#include <hip/hip_runtime.h>
#include <stdint.h>

// ---------------------------------------------------------------------------
// Tanh RNN on MI355X.
//   Phase 1: xproj_kernel — xp[t,b,:] = x[t,b,:] @ Wx^T + bx  (bf16 MFMA GEMM,
//            fp32 out written into the h_all region of d_out).
//   Phase 2: rnn_scan — persistent kernel, 256 WGs (1/CU), custom device-wide
//            barrier per timestep. Each WG owns a 32(batch) x 32(hidden)
//            output block; its Wh slice (32x1024 bf16 = 66 KB) stays in LDS
//            for all 512 steps. h ping-pongs through two global bf16 buffers.
// ---------------------------------------------------------------------------

typedef __attribute__((ext_vector_type(8))) short short8;   // 8 bf16 (4 VGPRs)
typedef __attribute__((ext_vector_type(4))) float floatx4;  // MFMA accumulator

#define HID    1024
#define BATCH  256
#define TSTEPS 512
#define NWG    256   // persistent workgroups in the scan (1 per CU)

__device__ __forceinline__ unsigned short f2bf(float f) {
  union { float f; unsigned u; } v; v.f = f;
  unsigned u = v.u;
  unsigned r = u + 0x7fffu + ((u >> 16) & 1u);  // round-to-nearest-even
  return (unsigned short)(r >> 16);
}

// ---------------------------------------------------------------------------
// Phase 1: xp = x @ Wx^T + bx.  M=131072 (t*256+b), N=1024, K=1024.
// 128x128 tile, BK=32, 256 threads (4 waves in 2x2), 16x16x32 bf16 MFMA.
// fp32 global loads converted to bf16 during LDS staging.
// Block order: m-fastest so concurrent blocks share the B (Wx) tile in L2 and
// x streams from HBM exactly once.
// ---------------------------------------------------------------------------
__global__ __launch_bounds__(256) void xproj_kernel(
    const float* __restrict__ x, const float* __restrict__ Wx,
    const float* __restrict__ bx, float* __restrict__ xp) {
  constexpr int LDK = 40;  // 32 + 8 bf16 pad -> 80 B rows, 2-way banks (free)
  __shared__ unsigned short As[128 * LDK];
  __shared__ unsigned short Bs[128 * LDK];
  const int tid  = threadIdx.x;
  const int lane = tid & 63;
  const int wave = tid >> 6;
  const int wm = wave & 1, wn = wave >> 1;
  const int q = lane >> 4, cl = lane & 15;
  const size_t m0 = (size_t)(blockIdx.x & 1023) * 128;  // 1024 m-tiles
  const int    n0 = (int)(blockIdx.x >> 10) * 128;      // 8 n-tiles

  floatx4 acc[4][4];
#pragma unroll
  for (int i = 0; i < 4; i++)
#pragma unroll
    for (int j = 0; j < 4; j++) acc[i][j] = floatx4{0.f, 0.f, 0.f, 0.f};

  for (int k0 = 0; k0 < HID; k0 += 32) {
    // stage A (x) and B (Wx) tiles: 128 rows x 32 cols fp32 -> bf16
#pragma unroll
    for (int it = 0; it < 4; it++) {
      int f = it * 256 + tid;        // 1024 float4 chunks per operand
      int row = f >> 3, c4 = f & 7;  // 8 float4 per row
      float4 va = *(const float4*)(x  + (m0 + row) * HID + k0 + c4 * 4);
      float4 vb = *(const float4*)(Wx + (size_t)(n0 + row) * HID + k0 + c4 * 4);
      uint2 pa, pb;
      pa.x = f2bf(va.x) | ((unsigned)f2bf(va.y) << 16);
      pa.y = f2bf(va.z) | ((unsigned)f2bf(va.w) << 16);
      pb.x = f2bf(vb.x) | ((unsigned)f2bf(vb.y) << 16);
      pb.y = f2bf(vb.z) | ((unsigned)f2bf(vb.w) << 16);
      *(uint2*)&As[row * LDK + c4 * 4] = pa;
      *(uint2*)&Bs[row * LDK + c4 * 4] = pb;
    }
    __syncthreads();
    short8 af[4], bfr[4];
#pragma unroll
    for (int i = 0; i < 4; i++)
      af[i] = *(const short8*)&As[(wm * 64 + i * 16 + cl) * LDK + q * 8];
#pragma unroll
    for (int j = 0; j < 4; j++)
      bfr[j] = *(const short8*)&Bs[(wn * 64 + j * 16 + cl) * LDK + q * 8];
#pragma unroll
    for (int i = 0; i < 4; i++)
#pragma unroll
      for (int j = 0; j < 4; j++)
        acc[i][j] = __builtin_amdgcn_mfma_f32_16x16x32_bf16(af[i], bfr[j],
                                                            acc[i][j], 0, 0, 0);
    __syncthreads();
  }
  // epilogue: C/D layout col=lane&15, row=quad*4+reg
#pragma unroll
  for (int j = 0; j < 4; j++) {
    int col = n0 + wn * 64 + j * 16 + cl;
    float bxv = bx[col];
#pragma unroll
    for (int i = 0; i < 4; i++) {
      size_t row = m0 + wm * 64 + i * 16 + q * 4;
#pragma unroll
      for (int r = 0; r < 4; r++)
        xp[(row + r) * HID + col] = acc[i][j][r] + bxv;
    }
  }
}

// ---------------------------------------------------------------------------
// Phase 2: persistent scan. Grid = 256 WGs x 256 threads, 1 WG/CU (132 KB LDS
// forces occupancy 1, and 256 WGs <= 256 CUs -> all co-resident).
// WG (bb,hh): batch rows bb*32..+31, hidden cols hh*32..+31.
// Per step: z = h @ WhT (MFMA, Wh slice resident in LDS) + xp + bh; h=tanh(z).
// xp is read from d_out's h_all region and overwritten in-place with h_t by
// the same thread (safe). Device-wide barrier: per-step counter in d_ws.
// ---------------------------------------------------------------------------
__global__ __launch_bounds__(256, 1) void rnn_scan(
    const float* __restrict__ Wh, const float* __restrict__ bh,
    float* __restrict__ out, unsigned short* __restrict__ hb0,
    unsigned short* __restrict__ hb1, int* __restrict__ ctr) {
  constexpr int LDW = 1032;  // 1024 + 8 bf16 pad -> 2064 B rows (16B aligned)
  __shared__ unsigned short Whs[32 * LDW];  // 66,048 B
  __shared__ unsigned short hs[32 * LDW];   // 66,048 B  (total 132 KB < 160 KB)
  const int tid  = threadIdx.x;
  const int lane = tid & 63, wave = tid >> 6;
  const int mt = wave & 1, nt = wave >> 1;   // wave's 16x16 tile in 32x32 block
  const int q = lane >> 4, cl = lane & 15;
  const int bb = (int)blockIdx.x >> 5;       // 0..7   batch block
  const int hh = (int)blockIdx.x & 31;       // 0..31  hidden slice

  // Load Wh slice rows hh*32..+31 (fp32 -> bf16) into LDS, once.
#pragma unroll 4
  for (int i = 0; i < 32; i++) {
    int f = i * 256 + tid;   // 8192 float4 chunks (32 rows x 256)
    int row = f >> 8, c4 = f & 255;
    float4 v = *(const float4*)(Wh + (size_t)(hh * 32 + row) * HID + c4 * 4);
    uint2 p;
    p.x = f2bf(v.x) | ((unsigned)f2bf(v.y) << 16);
    p.y = f2bf(v.z) | ((unsigned)f2bf(v.w) << 16);
    *(uint2*)&Whs[row * LDW + c4 * 4] = p;
  }
  const int   gcol = hh * 32 + nt * 16 + cl;
  const float bhv  = bh[gcol];
  float* const hall = out + (size_t)BATCH * HID;  // h_all region of d_out
  __syncthreads();

  for (int t = 0; t < TSTEPS; t++) {
    const unsigned short* hcur = (t & 1) ? hb1 : hb0;
    unsigned short*       hnxt = (t & 1) ? hb0 : hb1;

    // stage h rows bb*32..+31 (bf16) into LDS
#pragma unroll
    for (int i = 0; i < 16; i++) {
      int g = i * 256 + tid;  // 4096 uint4 chunks (32 rows x 128)
      int row = g >> 7, c8 = g & 127;
      uint4 v = *(const uint4*)(hcur + (size_t)(bb * 32 + row) * HID + c8 * 8);
      *(uint4*)&hs[row * LDW + c8 * 8] = v;
    }
    // prefetch this thread's 4 xp values (latency hidden behind K-loop)
    float xv[4];
    const size_t rbase = (size_t)t * BATCH + bb * 32 + mt * 16 + q * 4;
#pragma unroll
    for (int r = 0; r < 4; r++) xv[r] = hall[(rbase + r) * HID + gcol];
    __syncthreads();

    // z(16x16) = h(16x1024) @ Wh_slice^T(1024x16); 4 acc chains for ILP
    floatx4 a0 = {0.f,0.f,0.f,0.f}, a1 = {0.f,0.f,0.f,0.f};
    floatx4 a2 = {0.f,0.f,0.f,0.f}, a3 = {0.f,0.f,0.f,0.f};
    const unsigned short* ap = &hs[(mt * 16 + cl) * LDW + q * 8];
    const unsigned short* bp = &Whs[(nt * 16 + cl) * LDW + q * 8];
#pragma unroll
    for (int kb = 0; kb < 32; kb += 4) {
      a0 = __builtin_amdgcn_mfma_f32_16x16x32_bf16(
          *(const short8*)(ap + (kb + 0) * 32), *(const short8*)(bp + (kb + 0) * 32), a0, 0, 0, 0);
      a1 = __builtin_amdgcn_mfma_f32_16x16x32_bf16(
          *(const short8*)(ap + (kb + 1) * 32), *(const short8*)(bp + (kb + 1) * 32), a1, 0, 0, 0);
      a2 = __builtin_amdgcn_mfma_f32_16x16x32_bf16(
          *(const short8*)(ap + (kb + 2) * 32), *(const short8*)(bp + (kb + 2) * 32), a2, 0, 0, 0);
      a3 = __builtin_amdgcn_mfma_f32_16x16x32_bf16(
          *(const short8*)(ap + (kb + 3) * 32), *(const short8*)(bp + (kb + 3) * 32), a3, 0, 0, 0);
    }
    floatx4 acc = (a0 + a1) + (a2 + a3);

    // epilogue: h = tanh(z + xp + bh); write h_all (fp32, overwrites xp) and
    // next-step bf16 h buffer; final step also writes h_final.
#pragma unroll
    for (int r = 0; r < 4; r++) {
      float z  = acc[r] + xv[r] + bhv;
      float hv = tanhf(z);
      size_t grow = (size_t)(bb * 32 + mt * 16 + q * 4 + r);
      hall[((size_t)t * BATCH + grow) * HID + gcol] = hv;
      hnxt[grow * HID + gcol] = f2bf(hv);
      if (t == TSTEPS - 1) out[grow * HID + gcol] = hv;
    }

    // device-wide barrier (agent scope): release my stores, arrive, spin, acquire
    __threadfence();
    __syncthreads();
    if (tid == 0) {
      __hip_atomic_fetch_add(&ctr[t], 1, __ATOMIC_ACQ_REL, __HIP_MEMORY_SCOPE_AGENT);
      while (__hip_atomic_load(&ctr[t], __ATOMIC_RELAXED, __HIP_MEMORY_SCOPE_AGENT) < NWG) {
        __builtin_amdgcn_s_sleep(1);
      }
    }
    __syncthreads();
    __threadfence();  // invalidate caches before reading remote h writes
  }
}

// ---------------------------------------------------------------------------
extern "C" void kernel_launch(void* const* d_in, const int* in_sizes, int n_in,
                              void* d_out, int out_size, void* d_ws, size_t ws_size,
                              hipStream_t stream) {
  const float* x  = (const float*)d_in[0];
  const float* Wx = (const float*)d_in[1];
  const float* bx = (const float*)d_in[2];
  const float* Wh = (const float*)d_in[3];
  const float* bh = (const float*)d_in[4];
  float* out = (float*)d_out;

  // d_ws layout: [0,2048) step counters | 4096: hb0 (512 KB) | hb1 (512 KB)
  int* ctr = (int*)d_ws;
  unsigned short* hb0 = (unsigned short*)((char*)d_ws + 4096);
  unsigned short* hb1 = (unsigned short*)((char*)d_ws + 4096 + 524288);

  hipMemsetAsync(d_ws, 0, 4096 + 2 * 524288, stream);  // zero ctr + h0 = 0

  // Phase 1: xp -> h_all region of d_out (fp32)
  xproj_kernel<<<dim3(8192), dim3(256), 0, stream>>>(
      x, Wx, bx, out + (size_t)BATCH * HID);

  // Phase 2: persistent barriered scan
  rnn_scan<<<dim3(NWG), dim3(256), 0, stream>>>(Wh, bh, out, hb0, hb1, ctr);
}